// Round 3
// baseline (1826.644 us; speedup 1.0000x reference)
//
#include <hip/hip_runtime.h>

// Problem constants: IN_C=512, HID=64, LOC=64, GLOB=64, OUT_C=40, K=10
// Propagation on C=40 channels (Wl_loc folded through W2), y in fp16, split:
//   chunk A = ch 0..31  -> 64B rows (one aligned cache line per edge gather)
//   chunk B = ch 32..39 -> 16B rows (1.6MB working set, L2-resident per XCD)
// hid stays fp32 (160B rows).

typedef _Float16 half8 __attribute__((ext_vector_type(8)));

// ---------------- CSR build ----------------

__global__ __launch_bounds__(256) void count_kernel(const int* __restrict__ edge,
                                                    int* __restrict__ counts, int E) {
  int e = blockIdx.x * 256 + threadIdx.x;
  if (e < E) atomicAdd(&counts[edge[E + e]], 1);  // target = edge_index[1]
}

__global__ __launch_bounds__(256) void scanA_kernel(const int* __restrict__ counts,
                                                    int* __restrict__ incl,
                                                    int* __restrict__ partials, int Nn) {
  __shared__ int sbuf[256];
  int t = threadIdx.x;
  int base = blockIdx.x * 1024 + t * 4;
  int a0 = (base + 0 < Nn) ? counts[base + 0] : 0;
  int a1 = (base + 1 < Nn) ? counts[base + 1] : 0;
  int a2 = (base + 2 < Nn) ? counts[base + 2] : 0;
  int a3 = (base + 3 < Nn) ? counts[base + 3] : 0;
  int tot = a0 + a1 + a2 + a3;
  sbuf[t] = tot;
  __syncthreads();
  for (int off = 1; off < 256; off <<= 1) {
    int v = (t >= off) ? sbuf[t - off] : 0;
    __syncthreads();
    sbuf[t] += v;
    __syncthreads();
  }
  int excl = sbuf[t] - tot;
  if (base + 0 < Nn) incl[base + 0] = excl + a0;
  if (base + 1 < Nn) incl[base + 1] = excl + a0 + a1;
  if (base + 2 < Nn) incl[base + 2] = excl + a0 + a1 + a2;
  if (base + 3 < Nn) incl[base + 3] = excl + tot;
  if (t == 255) partials[blockIdx.x] = sbuf[255];
}

__global__ void scanB_kernel(const int* __restrict__ partials,
                             int* __restrict__ chunkoff, int B) {
  __shared__ int sbuf[256];
  int t = threadIdx.x;
  int v = (t < B) ? partials[t] : 0;
  sbuf[t] = v;
  __syncthreads();
  for (int off = 1; off < 256; off <<= 1) {
    int u = (t >= off) ? sbuf[t - off] : 0;
    __syncthreads();
    sbuf[t] += u;
    __syncthreads();
  }
  chunkoff[t] = sbuf[t] - v;  // exclusive
}

__global__ __launch_bounds__(256) void finalize_scan_kernel(const int* __restrict__ incl,
                                                            const int* __restrict__ chunkoff,
                                                            int* __restrict__ rowptr, int Nn) {
  int i = blockIdx.x * 256 + threadIdx.x;
  if (i < Nn) rowptr[i + 1] = incl[i] + chunkoff[i >> 10];
  if (i == 0) rowptr[0] = 0;
}

__global__ __launch_bounds__(256) void dinv_kernel(const int* __restrict__ counts,
                                                   float* __restrict__ dinv, int Nn) {
  int i = blockIdx.x * 256 + threadIdx.x;
  if (i < Nn) dinv[i] = rsqrtf((float)(counts[i] + 1));  // +1 self-loop
}

__global__ __launch_bounds__(256) void fill_kernel(const int* __restrict__ edge,
                                                   const int* __restrict__ rowptr,
                                                   int* __restrict__ cursor,
                                                   int* __restrict__ srcidx, int E) {
  int e = blockIdx.x * 256 + threadIdx.x;
  if (e < E) {
    int r = edge[e];          // source
    int c = edge[E + e];      // target
    int p = rowptr[c] + atomicAdd(&cursor[c], 1);
    srcidx[p] = r;            // source node index
  }
}

// ---------------- MLP stage 1: H = relu(X @ W1 + b1), [N,512]@[512,64] ----------------

__global__ __launch_bounds__(256) void mlp1_kernel(const float* __restrict__ X,
                                                   const float* __restrict__ W1,
                                                   const float* __restrict__ b1,
                                                   float* __restrict__ H, int Nn) {
  __shared__ float sXT[64][68];
  __shared__ float sW[64][68];
  int t = threadIdx.x;
  int m0 = blockIdx.x * 64;
  int tx = t & 15, ty = t >> 4;
  float acc[4][4];
#pragma unroll
  for (int i = 0; i < 4; ++i)
#pragma unroll
    for (int j = 0; j < 4; ++j) acc[i][j] = 0.f;

  for (int k0 = 0; k0 < 512; k0 += 64) {
#pragma unroll
    for (int i = 0; i < 4; ++i) {
      int lin = t + i * 256;
      int m = lin >> 4;
      int kq = lin & 15;
      int gr = m0 + m;
      float4 v = make_float4(0.f, 0.f, 0.f, 0.f);
      if (gr < Nn) v = *(const float4*)&X[(size_t)gr * 512 + k0 + kq * 4];
      sXT[kq * 4 + 0][m] = v.x;
      sXT[kq * 4 + 1][m] = v.y;
      sXT[kq * 4 + 2][m] = v.z;
      sXT[kq * 4 + 3][m] = v.w;
    }
#pragma unroll
    for (int i = 0; i < 4; ++i) {
      int lin = t + i * 256;
      int k = lin >> 4;
      int nq = lin & 15;
      float4 v = *(const float4*)&W1[(size_t)(k0 + k) * 64 + nq * 4];
      *(float4*)&sW[k][nq * 4] = v;
    }
    __syncthreads();
#pragma unroll 8
    for (int kk = 0; kk < 64; ++kk) {
      float4 a = *(const float4*)&sXT[kk][ty * 4];
      float4 b = *(const float4*)&sW[kk][tx * 4];
      float av[4] = {a.x, a.y, a.z, a.w};
      float bv[4] = {b.x, b.y, b.z, b.w};
#pragma unroll
      for (int i = 0; i < 4; ++i)
#pragma unroll
        for (int j = 0; j < 4; ++j) acc[i][j] += av[i] * bv[j];
    }
    __syncthreads();
  }
  float4 bb = *(const float4*)&b1[tx * 4];
  float bvv[4] = {bb.x, bb.y, bb.z, bb.w};
#pragma unroll
  for (int i = 0; i < 4; ++i) {
    int r = m0 + ty * 4 + i;
    if (r < Nn) {
      float4 o;
      o.x = fmaxf(acc[i][0] + bvv[0], 0.f);
      o.y = fmaxf(acc[i][1] + bvv[1], 0.f);
      o.z = fmaxf(acc[i][2] + bvv[2], 0.f);
      o.w = fmaxf(acc[i][3] + bvv[3], 0.f);
      *(float4*)&H[(size_t)r * 64 + tx * 4] = o;
    }
  }
}

// ---------------- M = W2 @ Wl[:64], cv = b2 @ Wl[:64] ----------------

__global__ void computeM_kernel(const float* __restrict__ W2, const float* __restrict__ Wl,
                                const float* __restrict__ b2, float* __restrict__ Mm,
                                float* __restrict__ cv) {
  int t = threadIdx.x;
  for (int idx = t; idx < 2560; idx += 256) {
    int k = idx / 40, o = idx - k * 40;
    float s = 0.f;
    for (int j = 0; j < 64; ++j) s += W2[k * 64 + j] * Wl[j * 40 + o];
    Mm[idx] = s;
  }
  if (t < 40) {
    float s = 0.f;
    for (int j = 0; j < 64; ++j) s += b2[j] * Wl[j * 40 + t];
    cv[t] = s;
  }
}

__global__ void zeropad_kernel(char* __restrict__ yAa, char* __restrict__ yAb,
                               char* __restrict__ yBa, char* __restrict__ yBb, int Nn) {
  int t = threadIdx.x;  // zero the pad row (index Nn) of all four buffers
  if (t < 32) {
    ((_Float16*)(yAa + (size_t)Nn * 64))[t] = (_Float16)0.f;
    ((_Float16*)(yBa + (size_t)Nn * 64))[t] = (_Float16)0.f;
  }
  if (t < 8) {
    ((_Float16*)(yAb + (size_t)Nn * 16))[t] = (_Float16)0.f;
    ((_Float16*)(yBb + (size_t)Nn * 16))[t] = (_Float16)0.f;
  }
}

// ---------------- z0: y0 = dinv * (H @ M + cv) (fp16 split); hid = temp[0]*y0 ----------------

__global__ __launch_bounds__(256) void z0_kernel(const float* __restrict__ H,
                                                 const float* __restrict__ Mm,
                                                 const float* __restrict__ cv,
                                                 const float* __restrict__ dinv,
                                                 const float* __restrict__ temp,
                                                 char* __restrict__ y0a,
                                                 char* __restrict__ y0b,
                                                 float* __restrict__ hid, int Nn) {
  __shared__ float sM[2624];
  __shared__ float sc[40];
  int t = threadIdx.x;
  for (int i = t; i < 2560; i += 256) sM[i] = Mm[i];
  for (int i = 2560 + t; i < 2624; i += 256) sM[i] = 0.f;
  if (t < 40) sc[t] = cv[t];
  __syncthreads();
  int wid = t >> 6, lane = t & 63;
  int node = blockIdx.x * 4 + wid;
  if (node < Nn) {
    float h = H[(size_t)node * 64 + lane];
    float acc = (lane < 40) ? sc[lane] : 0.f;
#pragma unroll 8
    for (int k = 0; k < 64; ++k) acc += __shfl(h, k) * sM[k * 40 + lane];
    if (lane < 40) {
      float di = dinv[node];
      float y = di * acc;
      if (lane < 32)
        ((_Float16*)(y0a + (size_t)node * 64))[lane] = (_Float16)y;
      else
        ((_Float16*)(y0b + (size_t)node * 16))[lane - 32] = (_Float16)y;
      hid[(size_t)node * 40 + lane] = temp[0] * y;
    }
  }
}

// ---------------- propagation hop, two channel passes in one launch ----------------
// Pass A (blocks [0, nodeBlocks)): ch 0..31, 64B rows; 16 edge-groups x 4 lanes.
// Pass B (blocks [nodeBlocks, 2*nodeBlocks)): ch 32..39, 16B rows; 1 edge/lane.
// y_next[c] = dinv[c]^2 * (sum_{e->c} y[src_e] + y[c]);  hid += temp[k]*y_next

__global__ __launch_bounds__(256) void prop_kernel(const char* __restrict__ yin_a,
                                                   const char* __restrict__ yin_b,
                                                   char* __restrict__ yout_a,
                                                   char* __restrict__ yout_b,
                                                   float* __restrict__ hid,
                                                   const int* __restrict__ srcidx,
                                                   const int* __restrict__ rowptr,
                                                   const float* __restrict__ dinv,
                                                   const float* __restrict__ temp,
                                                   int kidx, int Nn, int nodeBlocks) {
  __shared__ float red[4][64][8];
  int t = threadIdx.x, wid = t >> 6, lane = t & 63;
  if ((int)blockIdx.x < nodeBlocks) {
    // ---- pass A: channels 0..31 ----
    int node = blockIdx.x * 4 + wid;
    int sub = lane >> 2, cl = lane & 3;
    int claneoff = cl << 4;
    float a[8];
#pragma unroll
    for (int i = 0; i < 8; ++i) a[i] = 0.f;
    if (node < Nn) {
      int start = rowptr[node], end = rowptr[node + 1];
      for (int b0 = start; b0 < end; b0 += 64) {
        int j = b0 + lane;
        int idx = (j < end) ? srcidx[j] : Nn;  // pad row -> zeros
        int rem = end - b0;
        int cnt = rem < 64 ? rem : 64;
        int tmax = (cnt + 15) >> 4;
        for (int tt = 0; tt < tmax; ++tt) {
          int s = __shfl(idx, tt * 16 + sub);
          half8 v = *(const half8*)(yin_a + (size_t)s * 64 + claneoff);
#pragma unroll
          for (int i = 0; i < 8; ++i) a[i] += (float)v[i];
        }
      }
    }
#pragma unroll
    for (int i = 0; i < 8; ++i) red[wid][lane][i] = a[i];
    __syncthreads();
    if (node < Nn && lane < 4) {
      float s[8];
#pragma unroll
      for (int i = 0; i < 8; ++i) s[i] = 0.f;
#pragma unroll
      for (int g = 0; g < 16; ++g)
#pragma unroll
        for (int i = 0; i < 8; ++i) s[i] += red[wid][g * 4 + lane][i];
      float di = dinv[node];
      float m = di * di;
      half8 self = *(const half8*)(yin_a + (size_t)node * 64 + (lane << 4));
      float yn[8];
      half8 outv;
#pragma unroll
      for (int i = 0; i < 8; ++i) {
        yn[i] = m * (s[i] + (float)self[i]);
        outv[i] = (_Float16)yn[i];
      }
      *(half8*)(yout_a + (size_t)node * 64 + (lane << 4)) = outv;
      float tk = temp[kidx];
      float* hp = &hid[(size_t)node * 40 + lane * 8];
      float4 h0 = *(float4*)hp;
      float4 h1 = *(float4*)(hp + 4);
      h0.x += tk * yn[0]; h0.y += tk * yn[1]; h0.z += tk * yn[2]; h0.w += tk * yn[3];
      h1.x += tk * yn[4]; h1.y += tk * yn[5]; h1.z += tk * yn[6]; h1.w += tk * yn[7];
      *(float4*)hp = h0;
      *(float4*)(hp + 4) = h1;
    }
  } else {
    // ---- pass B: channels 32..39, one edge per lane ----
    int node = (blockIdx.x - nodeBlocks) * 4 + wid;
    if (node < Nn) {
      float a[8];
#pragma unroll
      for (int i = 0; i < 8; ++i) a[i] = 0.f;
      int start = rowptr[node], end = rowptr[node + 1];
      for (int b0 = start; b0 < end; b0 += 64) {
        int j = b0 + lane;
        int idx = (j < end) ? srcidx[j] : Nn;  // pad row -> zeros
        half8 v = *(const half8*)(yin_b + (size_t)idx * 16);
#pragma unroll
        for (int i = 0; i < 8; ++i) a[i] += (float)v[i];
      }
#pragma unroll
      for (int d = 32; d >= 1; d >>= 1)
#pragma unroll
        for (int i = 0; i < 8; ++i) a[i] += __shfl_xor(a[i], d);
      if (lane == 0) {
        float di = dinv[node];
        float m = di * di;
        half8 self = *(const half8*)(yin_b + (size_t)node * 16);
        float yn[8];
        half8 outv;
#pragma unroll
        for (int i = 0; i < 8; ++i) {
          yn[i] = m * (a[i] + (float)self[i]);
          outv[i] = (_Float16)yn[i];
        }
        *(half8*)(yout_b + (size_t)node * 16) = outv;
        float tk = temp[kidx];
        float* hp = &hid[(size_t)node * 40 + 32];
        float4 h0 = *(float4*)hp;
        float4 h1 = *(float4*)(hp + 4);
        h0.x += tk * yn[0]; h0.y += tk * yn[1]; h0.z += tk * yn[2]; h0.w += tk * yn[3];
        h1.x += tk * yn[4]; h1.y += tk * yn[5]; h1.z += tk * yn[6]; h1.w += tk * yn[7];
        *(float4*)hp = h0;
        *(float4*)(hp + 4) = h1;
      }
    }
  }
}

// ---------------- final: out = sqrt(deg)*hid + glob @ Wl[64:] + bl ----------------

__global__ __launch_bounds__(256) void final_kernel(const float* __restrict__ glob,
                                                    const float* __restrict__ Wl,
                                                    const float* __restrict__ bl,
                                                    const float* __restrict__ hid,
                                                    const int* __restrict__ counts,
                                                    const float* __restrict__ dinv,
                                                    float* __restrict__ out, int Nn) {
  __shared__ float sW[2624];
  __shared__ float sb[40];
  int t = threadIdx.x;
  for (int i = t; i < 2560; i += 256) sW[i] = Wl[2560 + i];  // Wl[64:128,:]
  for (int i = 2560 + t; i < 2624; i += 256) sW[i] = 0.f;
  if (t < 40) sb[t] = bl[t];
  __syncthreads();
  int wid = t >> 6, lane = t & 63;
  int node = blockIdx.x * 4 + wid;
  if (node < Nn) {
    float g = glob[(size_t)node * 64 + lane];
    float acc = (lane < 40) ? sb[lane] : 0.f;
#pragma unroll 8
    for (int k = 0; k < 64; ++k) acc += __shfl(g, k) * sW[k * 40 + lane];
    if (lane < 40) {
      float sc = (float)(counts[node] + 1) * dinv[node];  // sqrt(deg)
      out[(size_t)node * 40 + lane] = sc * hid[(size_t)node * 40 + lane] + acc;
    }
  }
}

// ---------------- host ----------------

extern "C" void kernel_launch(void* const* d_in, const int* in_sizes, int n_in,
                              void* d_out, int out_size, void* d_ws, size_t ws_size,
                              hipStream_t stream) {
  const float* X    = (const float*)d_in[0];
  const int*   edge = (const int*)d_in[1];
  const float* glob = (const float*)d_in[2];
  const float* W1   = (const float*)d_in[3];
  const float* b1   = (const float*)d_in[4];
  const float* W2   = (const float*)d_in[5];
  const float* b2   = (const float*)d_in[6];
  const float* temp = (const float*)d_in[7];
  const float* Wl   = (const float*)d_in[8];
  const float* bl   = (const float*)d_in[9];
  float* out = (float*)d_out;

  int Nn = in_sizes[0] / 512;     // 100000
  int E  = in_sizes[1] / 2;       // 3200000
  int Kk = in_sizes[7] - 1;       // 10

  char* p = (char*)d_ws;
  auto alloc = [&](size_t bytes) {
    char* r = p;
    p += (bytes + 255) & ~(size_t)255;
    return r;
  };
  int*   counts   = (int*)alloc((size_t)Nn * 4);
  int*   rowptr   = (int*)alloc((size_t)(Nn + 1) * 4);
  int*   incl     = (int*)alloc((size_t)Nn * 4);
  int*   partials = (int*)alloc(256 * 4);
  int*   chunkoff = (int*)alloc(256 * 4);
  int*   cursor   = (int*)alloc((size_t)Nn * 4);
  float* dinv     = (float*)alloc((size_t)Nn * 4);
  int*   srcidx   = (int*)alloc((size_t)E * 4);
  float* Hbuf     = (float*)alloc((size_t)Nn * 64 * 4);
  float* Mm       = (float*)alloc(2560 * 4);
  float* cv       = (float*)alloc(64 * 4);
  char*  yAa      = (char*)alloc((size_t)(Nn + 1) * 64);  // ch 0..31, fp16
  char*  yBa      = (char*)alloc((size_t)(Nn + 1) * 64);
  char*  yAb      = (char*)alloc((size_t)(Nn + 1) * 16);  // ch 32..39, fp16
  char*  yBb      = (char*)alloc((size_t)(Nn + 1) * 16);
  float* hid      = (float*)alloc((size_t)Nn * 40 * 4);

  hipMemsetAsync(counts, 0, (size_t)Nn * 4, stream);
  hipMemsetAsync(cursor, 0, (size_t)Nn * 4, stream);

  count_kernel<<<(E + 255) / 256, 256, 0, stream>>>(edge, counts, E);
  int B = (Nn + 1023) / 1024;
  scanA_kernel<<<B, 256, 0, stream>>>(counts, incl, partials, Nn);
  scanB_kernel<<<1, 256, 0, stream>>>(partials, chunkoff, B);
  finalize_scan_kernel<<<(Nn + 255) / 256, 256, 0, stream>>>(incl, chunkoff, rowptr, Nn);
  dinv_kernel<<<(Nn + 255) / 256, 256, 0, stream>>>(counts, dinv, Nn);
  fill_kernel<<<(E + 255) / 256, 256, 0, stream>>>(edge, rowptr, cursor, srcidx, E);

  mlp1_kernel<<<(Nn + 63) / 64, 256, 0, stream>>>(X, W1, b1, Hbuf, Nn);
  computeM_kernel<<<1, 256, 0, stream>>>(W2, Wl, b2, Mm, cv);
  zeropad_kernel<<<1, 64, 0, stream>>>(yAa, yAb, yBa, yBb, Nn);

  int nodeBlocks = (Nn + 3) / 4;
  z0_kernel<<<nodeBlocks, 256, 0, stream>>>(Hbuf, Mm, cv, dinv, temp, yAa, yAb, hid, Nn);

  char* yina = yAa; char* yinb = yAb;
  char* youta = yBa; char* youtb = yBb;
  for (int k = 1; k <= Kk; ++k) {
    prop_kernel<<<2 * nodeBlocks, 256, 0, stream>>>(yina, yinb, youta, youtb, hid,
                                                    srcidx, rowptr, dinv, temp, k, Nn,
                                                    nodeBlocks);
    char* ta = yina; yina = youta; youta = ta;
    char* tb = yinb; yinb = youtb; youtb = tb;
  }

  final_kernel<<<nodeBlocks, 256, 0, stream>>>(glob, Wl, bl, hid, counts, dinv, out, Nn);
}

// Round 4
// 1400.428 us; speedup vs baseline: 1.3043x; 1.3043x over previous
//
#include <hip/hip_runtime.h>

// Problem constants: IN_C=512, HID=64, LOC=64, GLOB=64, OUT_C=40, K=10
// Propagation on C=40 channels (Wl_loc folded through W2).
// y stored as fp16, 40ch = 80B, padded to 128B stride (one gather line per edge).
// hid stays fp32. Inner gather loop has compile-time trip count (5) so the
// compiler fully unrolls -> 5 independent bpermute+gather pairs in flight.

typedef _Float16 half8 __attribute__((ext_vector_type(8)));

// ---------------- CSR build ----------------

__global__ __launch_bounds__(256) void count_kernel(const int* __restrict__ edge,
                                                    int* __restrict__ counts, int E) {
  int e = blockIdx.x * 256 + threadIdx.x;
  if (e < E) atomicAdd(&counts[edge[E + e]], 1);  // target = edge_index[1]
}

__global__ __launch_bounds__(256) void scanA_kernel(const int* __restrict__ counts,
                                                    int* __restrict__ incl,
                                                    int* __restrict__ partials, int Nn) {
  __shared__ int sbuf[256];
  int t = threadIdx.x;
  int base = blockIdx.x * 1024 + t * 4;
  int a0 = (base + 0 < Nn) ? counts[base + 0] : 0;
  int a1 = (base + 1 < Nn) ? counts[base + 1] : 0;
  int a2 = (base + 2 < Nn) ? counts[base + 2] : 0;
  int a3 = (base + 3 < Nn) ? counts[base + 3] : 0;
  int tot = a0 + a1 + a2 + a3;
  sbuf[t] = tot;
  __syncthreads();
  for (int off = 1; off < 256; off <<= 1) {
    int v = (t >= off) ? sbuf[t - off] : 0;
    __syncthreads();
    sbuf[t] += v;
    __syncthreads();
  }
  int excl = sbuf[t] - tot;
  if (base + 0 < Nn) incl[base + 0] = excl + a0;
  if (base + 1 < Nn) incl[base + 1] = excl + a0 + a1;
  if (base + 2 < Nn) incl[base + 2] = excl + a0 + a1 + a2;
  if (base + 3 < Nn) incl[base + 3] = excl + tot;
  if (t == 255) partials[blockIdx.x] = sbuf[255];
}

__global__ void scanB_kernel(const int* __restrict__ partials,
                             int* __restrict__ chunkoff, int B) {
  __shared__ int sbuf[256];
  int t = threadIdx.x;
  int v = (t < B) ? partials[t] : 0;
  sbuf[t] = v;
  __syncthreads();
  for (int off = 1; off < 256; off <<= 1) {
    int u = (t >= off) ? sbuf[t - off] : 0;
    __syncthreads();
    sbuf[t] += u;
    __syncthreads();
  }
  chunkoff[t] = sbuf[t] - v;  // exclusive
}

__global__ __launch_bounds__(256) void finalize_scan_kernel(const int* __restrict__ incl,
                                                            const int* __restrict__ chunkoff,
                                                            int* __restrict__ rowptr, int Nn) {
  int i = blockIdx.x * 256 + threadIdx.x;
  if (i < Nn) rowptr[i + 1] = incl[i] + chunkoff[i >> 10];
  if (i == 0) rowptr[0] = 0;
}

__global__ __launch_bounds__(256) void dinv_kernel(const int* __restrict__ counts,
                                                   float* __restrict__ dinv, int Nn) {
  int i = blockIdx.x * 256 + threadIdx.x;
  if (i < Nn) dinv[i] = rsqrtf((float)(counts[i] + 1));  // +1 self-loop
}

__global__ __launch_bounds__(256) void fill_kernel(const int* __restrict__ edge,
                                                   const int* __restrict__ rowptr,
                                                   int* __restrict__ cursor,
                                                   int* __restrict__ srcoff, int E) {
  int e = blockIdx.x * 256 + threadIdx.x;
  if (e < E) {
    int r = edge[e];          // source
    int c = edge[E + e];      // target
    int p = rowptr[c] + atomicAdd(&cursor[c], 1);
    srcoff[p] = r * 128;      // byte offset of fp16 source row (128B stride)
  }
}

// ---------------- MLP stage 1: H = relu(X @ W1 + b1), [N,512]@[512,64] ----------------

__global__ __launch_bounds__(256) void mlp1_kernel(const float* __restrict__ X,
                                                   const float* __restrict__ W1,
                                                   const float* __restrict__ b1,
                                                   float* __restrict__ H, int Nn) {
  __shared__ float sXT[64][68];
  __shared__ float sW[64][68];
  int t = threadIdx.x;
  int m0 = blockIdx.x * 64;
  int tx = t & 15, ty = t >> 4;
  float acc[4][4];
#pragma unroll
  for (int i = 0; i < 4; ++i)
#pragma unroll
    for (int j = 0; j < 4; ++j) acc[i][j] = 0.f;

  for (int k0 = 0; k0 < 512; k0 += 64) {
#pragma unroll
    for (int i = 0; i < 4; ++i) {
      int lin = t + i * 256;
      int m = lin >> 4;
      int kq = lin & 15;
      int gr = m0 + m;
      float4 v = make_float4(0.f, 0.f, 0.f, 0.f);
      if (gr < Nn) v = *(const float4*)&X[(size_t)gr * 512 + k0 + kq * 4];
      sXT[kq * 4 + 0][m] = v.x;
      sXT[kq * 4 + 1][m] = v.y;
      sXT[kq * 4 + 2][m] = v.z;
      sXT[kq * 4 + 3][m] = v.w;
    }
#pragma unroll
    for (int i = 0; i < 4; ++i) {
      int lin = t + i * 256;
      int k = lin >> 4;
      int nq = lin & 15;
      float4 v = *(const float4*)&W1[(size_t)(k0 + k) * 64 + nq * 4];
      *(float4*)&sW[k][nq * 4] = v;
    }
    __syncthreads();
#pragma unroll 8
    for (int kk = 0; kk < 64; ++kk) {
      float4 a = *(const float4*)&sXT[kk][ty * 4];
      float4 b = *(const float4*)&sW[kk][tx * 4];
      float av[4] = {a.x, a.y, a.z, a.w};
      float bv[4] = {b.x, b.y, b.z, b.w};
#pragma unroll
      for (int i = 0; i < 4; ++i)
#pragma unroll
        for (int j = 0; j < 4; ++j) acc[i][j] += av[i] * bv[j];
    }
    __syncthreads();
  }
  float4 bb = *(const float4*)&b1[tx * 4];
  float bvv[4] = {bb.x, bb.y, bb.z, bb.w};
#pragma unroll
  for (int i = 0; i < 4; ++i) {
    int r = m0 + ty * 4 + i;
    if (r < Nn) {
      float4 o;
      o.x = fmaxf(acc[i][0] + bvv[0], 0.f);
      o.y = fmaxf(acc[i][1] + bvv[1], 0.f);
      o.z = fmaxf(acc[i][2] + bvv[2], 0.f);
      o.w = fmaxf(acc[i][3] + bvv[3], 0.f);
      *(float4*)&H[(size_t)r * 64 + tx * 4] = o;
    }
  }
}

// ---------------- M = W2 @ Wl[:64], cv = b2 @ Wl[:64] ----------------

__global__ void computeM_kernel(const float* __restrict__ W2, const float* __restrict__ Wl,
                                const float* __restrict__ b2, float* __restrict__ Mm,
                                float* __restrict__ cv) {
  int t = threadIdx.x;
  for (int idx = t; idx < 2560; idx += 256) {
    int k = idx / 40, o = idx - k * 40;
    float s = 0.f;
    for (int j = 0; j < 64; ++j) s += W2[k * 64 + j] * Wl[j * 40 + o];
    Mm[idx] = s;
  }
  if (t < 40) {
    float s = 0.f;
    for (int j = 0; j < 64; ++j) s += b2[j] * Wl[j * 40 + t];
    cv[t] = s;
  }
}

__global__ void zeropad_kernel(char* __restrict__ yA, char* __restrict__ yB, int Nn) {
  int t = threadIdx.x;  // 64 threads zero the 128B pad row of each buffer
  ((_Float16*)(yA + (size_t)Nn * 128))[t] = (_Float16)0.f;
  ((_Float16*)(yB + (size_t)Nn * 128))[t] = (_Float16)0.f;
}

// ---------------- z0: y0 = dinv * (H @ M + cv) (fp16); hid = temp[0]*y0 (fp32) ----------------

__global__ __launch_bounds__(256) void z0_kernel(const float* __restrict__ H,
                                                 const float* __restrict__ Mm,
                                                 const float* __restrict__ cv,
                                                 const float* __restrict__ dinv,
                                                 const float* __restrict__ temp,
                                                 char* __restrict__ y0,
                                                 float* __restrict__ hid, int Nn) {
  __shared__ float sM[2624];
  __shared__ float sc[40];
  int t = threadIdx.x;
  for (int i = t; i < 2560; i += 256) sM[i] = Mm[i];
  for (int i = 2560 + t; i < 2624; i += 256) sM[i] = 0.f;
  if (t < 40) sc[t] = cv[t];
  __syncthreads();
  int wid = t >> 6, lane = t & 63;
  int node = blockIdx.x * 4 + wid;
  if (node < Nn) {
    float h = H[(size_t)node * 64 + lane];
    float acc = (lane < 40) ? sc[lane] : 0.f;
#pragma unroll 8
    for (int k = 0; k < 64; ++k) acc += __shfl(h, k) * sM[k * 40 + lane];
    if (lane < 40) {
      float di = dinv[node];
      float y = di * acc;
      ((_Float16*)(y0 + (size_t)node * 128))[lane] = (_Float16)y;
      hid[(size_t)node * 40 + lane] = temp[0] * y;
    }
  }
}

// ---------------- propagation hop (fp16 y, 128B rows) ----------------
// y_next[c] = dinv[c]^2 * (sum_{e->c} y[src_e] + y[c]);  hid += temp[k]*y_next
// wave per node; 12 edge-groups x 5 lanes; each lane one half8 (16B) of the 80B row.
// Inner loop trip count is a compile-time 5: invalid slots resolve to the zero
// pad row (L1-hot), letting the compiler unroll and keep 5 gathers in flight.

__global__ __launch_bounds__(256) void prop_kernel(const char* __restrict__ yin,
                                                   char* __restrict__ yout,
                                                   float* __restrict__ hid,
                                                   const int* __restrict__ srcoff,
                                                   const int* __restrict__ rowptr,
                                                   const float* __restrict__ dinv,
                                                   const float* __restrict__ temp,
                                                   int kidx, int Nn) {
  __shared__ float red[4][60][8];
  int t = threadIdx.x, wid = t >> 6, lane = t & 63;
  int node = blockIdx.x * 4 + wid;
  int sub = lane / 5;        // edge group 0..11 (12 for lanes 60..63 -> zero row)
  int cl = lane - sub * 5;   // half8 slot 0..4
  const int zoff = Nn * 128; // zero pad row byte offset
  float a0 = 0.f, a1 = 0.f, a2 = 0.f, a3 = 0.f, a4 = 0.f, a5 = 0.f, a6 = 0.f, a7 = 0.f;
  if (node < Nn) {
    int start = rowptr[node], end = rowptr[node + 1];
    int claneoff = cl << 4;
    for (int b0 = start; b0 < end; b0 += 60) {
      int j = b0 + lane;
      int moff = (lane < 60 && j < end) ? srcoff[j] : zoff;
#pragma unroll
      for (int tt = 0; tt < 5; ++tt) {
        int off = __shfl(moff, tt * 12 + sub);  // invalid/pad slots -> zoff
        half8 v = *(const half8*)(yin + off + claneoff);
        a0 += (float)v[0]; a1 += (float)v[1]; a2 += (float)v[2]; a3 += (float)v[3];
        a4 += (float)v[4]; a5 += (float)v[5]; a6 += (float)v[6]; a7 += (float)v[7];
      }
    }
  }
  if (lane < 60) {
    red[wid][lane][0] = a0; red[wid][lane][1] = a1;
    red[wid][lane][2] = a2; red[wid][lane][3] = a3;
    red[wid][lane][4] = a4; red[wid][lane][5] = a5;
    red[wid][lane][6] = a6; red[wid][lane][7] = a7;
  }
  __syncthreads();
  if (node < Nn && lane < 5) {
    float s[8];
#pragma unroll
    for (int i = 0; i < 8; ++i) s[i] = 0.f;
#pragma unroll
    for (int g = 0; g < 12; ++g)
#pragma unroll
      for (int i = 0; i < 8; ++i) s[i] += red[wid][g * 5 + lane][i];
    float di = dinv[node];
    float m = di * di;
    half8 self = *(const half8*)(yin + (size_t)node * 128 + (lane << 4));
    float yn[8];
    half8 outv;
#pragma unroll
    for (int i = 0; i < 8; ++i) {
      yn[i] = m * (s[i] + (float)self[i]);
      outv[i] = (_Float16)yn[i];
    }
    *(half8*)(yout + (size_t)node * 128 + (lane << 4)) = outv;
    float tk = temp[kidx];
    float* hp = &hid[(size_t)node * 40 + lane * 8];
    float4 h0 = *(float4*)hp;
    float4 h1 = *(float4*)(hp + 4);
    h0.x += tk * yn[0]; h0.y += tk * yn[1]; h0.z += tk * yn[2]; h0.w += tk * yn[3];
    h1.x += tk * yn[4]; h1.y += tk * yn[5]; h1.z += tk * yn[6]; h1.w += tk * yn[7];
    *(float4*)hp = h0;
    *(float4*)(hp + 4) = h1;
  }
}

// ---------------- final: out = sqrt(deg)*hid + glob @ Wl[64:] + bl ----------------

__global__ __launch_bounds__(256) void final_kernel(const float* __restrict__ glob,
                                                    const float* __restrict__ Wl,
                                                    const float* __restrict__ bl,
                                                    const float* __restrict__ hid,
                                                    const int* __restrict__ counts,
                                                    const float* __restrict__ dinv,
                                                    float* __restrict__ out, int Nn) {
  __shared__ float sW[2624];
  __shared__ float sb[40];
  int t = threadIdx.x;
  for (int i = t; i < 2560; i += 256) sW[i] = Wl[2560 + i];  // Wl[64:128,:]
  for (int i = 2560 + t; i < 2624; i += 256) sW[i] = 0.f;
  if (t < 40) sb[t] = bl[t];
  __syncthreads();
  int wid = t >> 6, lane = t & 63;
  int node = blockIdx.x * 4 + wid;
  if (node < Nn) {
    float g = glob[(size_t)node * 64 + lane];
    float acc = (lane < 40) ? sb[lane] : 0.f;
#pragma unroll 8
    for (int k = 0; k < 64; ++k) acc += __shfl(g, k) * sW[k * 40 + lane];
    if (lane < 40) {
      float sc = (float)(counts[node] + 1) * dinv[node];  // sqrt(deg)
      out[(size_t)node * 40 + lane] = sc * hid[(size_t)node * 40 + lane] + acc;
    }
  }
}

// ---------------- host ----------------

extern "C" void kernel_launch(void* const* d_in, const int* in_sizes, int n_in,
                              void* d_out, int out_size, void* d_ws, size_t ws_size,
                              hipStream_t stream) {
  const float* X    = (const float*)d_in[0];
  const int*   edge = (const int*)d_in[1];
  const float* glob = (const float*)d_in[2];
  const float* W1   = (const float*)d_in[3];
  const float* b1   = (const float*)d_in[4];
  const float* W2   = (const float*)d_in[5];
  const float* b2   = (const float*)d_in[6];
  const float* temp = (const float*)d_in[7];
  const float* Wl   = (const float*)d_in[8];
  const float* bl   = (const float*)d_in[9];
  float* out = (float*)d_out;

  int Nn = in_sizes[0] / 512;     // 100000
  int E  = in_sizes[1] / 2;       // 3200000
  int Kk = in_sizes[7] - 1;       // 10

  char* p = (char*)d_ws;
  auto alloc = [&](size_t bytes) {
    char* r = p;
    p += (bytes + 255) & ~(size_t)255;
    return r;
  };
  int*   counts   = (int*)alloc((size_t)Nn * 4);
  int*   rowptr   = (int*)alloc((size_t)(Nn + 1) * 4);
  int*   incl     = (int*)alloc((size_t)Nn * 4);
  int*   partials = (int*)alloc(256 * 4);
  int*   chunkoff = (int*)alloc(256 * 4);
  int*   cursor   = (int*)alloc((size_t)Nn * 4);
  float* dinv     = (float*)alloc((size_t)Nn * 4);
  int*   srcoff   = (int*)alloc((size_t)E * 4);
  float* Hbuf     = (float*)alloc((size_t)Nn * 64 * 4);
  float* Mm       = (float*)alloc(2560 * 4);
  float* cv       = (float*)alloc(64 * 4);
  char*  yA       = (char*)alloc((size_t)(Nn + 1) * 128);  // fp16, 128B stride
  char*  yB       = (char*)alloc((size_t)(Nn + 1) * 128);
  float* hid      = (float*)alloc((size_t)Nn * 40 * 4);

  hipMemsetAsync(counts, 0, (size_t)Nn * 4, stream);
  hipMemsetAsync(cursor, 0, (size_t)Nn * 4, stream);

  count_kernel<<<(E + 255) / 256, 256, 0, stream>>>(edge, counts, E);
  int B = (Nn + 1023) / 1024;
  scanA_kernel<<<B, 256, 0, stream>>>(counts, incl, partials, Nn);
  scanB_kernel<<<1, 256, 0, stream>>>(partials, chunkoff, B);
  finalize_scan_kernel<<<(Nn + 255) / 256, 256, 0, stream>>>(incl, chunkoff, rowptr, Nn);
  dinv_kernel<<<(Nn + 255) / 256, 256, 0, stream>>>(counts, dinv, Nn);
  fill_kernel<<<(E + 255) / 256, 256, 0, stream>>>(edge, rowptr, cursor, srcoff, E);

  mlp1_kernel<<<(Nn + 63) / 64, 256, 0, stream>>>(X, W1, b1, Hbuf, Nn);
  computeM_kernel<<<1, 256, 0, stream>>>(W2, Wl, b2, Mm, cv);
  zeropad_kernel<<<1, 64, 0, stream>>>(yA, yB, Nn);

  int nodeBlocks = (Nn + 3) / 4;
  z0_kernel<<<nodeBlocks, 256, 0, stream>>>(Hbuf, Mm, cv, dinv, temp, yA, hid, Nn);

  char* yin = yA;
  char* yout = yB;
  for (int k = 1; k <= Kk; ++k) {
    prop_kernel<<<nodeBlocks, 256, 0, stream>>>(yin, yout, hid, srcoff, rowptr, dinv,
                                                temp, k, Nn);
    char* tmpp = yin; yin = yout; yout = tmpp;
  }

  final_kernel<<<nodeBlocks, 256, 0, stream>>>(glob, Wl, bl, hid, counts, dinv, out, Nn);
}